// Round 8
// baseline (208.835 us; speedup 1.0000x reference)
//
#include <hip/hip_runtime.h>
#include <hip/hip_bf16.h>
#include <cstdint>

#define B 2
#define NH 4
#define HD 32
#define DIM 128
#define CX 256
#define CY 512
#define PX 4096
#define PY 1024
#define QKV 384
#define GAMMA 0.17677669529663687f

typedef unsigned short u16;
typedef unsigned int u32;

using short8 = __attribute__((ext_vector_type(8))) short;
using f32x4  = __attribute__((ext_vector_type(4))) float;

__device__ __forceinline__ float bf2f(u32 h) {
  union { u32 u; float f; } v; v.u = (h & 0xffffu) << 16; return v.f;
}
__device__ __forceinline__ u16 f2bf(float f) {
  u32 u = __float_as_uint(f);
  u32 r = (u + 0x7fffu + ((u >> 16) & 1u)) >> 16;
  return (u16)r;
}
__device__ __forceinline__ void gl_lds16(const u16* g, u16* l) {
  __builtin_amdgcn_global_load_lds(
      (const __attribute__((address_space(1))) void*)g,
      (__attribute__((address_space(3))) void*)l, 16, 0, 0);
}

#define N_X   (B * CX * PX)
#define N_Y   (B * CY * PY)
#define N_WX  (QKV * CX)
#define N_BX  (QKV)
#define N_WY  (QKV * CY)
#define N_BY  (QKV)
#define N_WPX (CX * DIM)
#define N_BPX (CX)
#define N_WPY (CY * DIM)
#define N_BPY (CY)

// ---- workspace layout (u16 element offsets, all 16B-aligned) ----
enum : size_t {
  OFF_FLAGS = 0,
  OFF_CWX   = 32,
  OFF_CBX   = OFF_CWX  + N_WX,
  OFF_CWY   = OFF_CBX  + N_BX,
  OFF_CBY   = OFF_CWY  + N_WY,
  OFF_CWPX  = OFF_CBY  + N_BY,
  OFF_CBPX  = OFF_CWPX + N_WPX,
  OFF_CWPY  = OFF_CBPX + N_BPX,
  OFF_CBPY  = OFF_CWPY + N_WPY,
  OFF_XT    = OFF_CBPY + N_BPY,
  OFF_YT    = OFF_XT   + (size_t)B * PX * CX,
  OFF_QKTX  = OFF_YT   + (size_t)B * PY * CY,
  OFF_QKTY  = OFF_QKTX + (size_t)B * PX * 256,
  OFF_VCX   = OFF_QKTY + (size_t)B * PY * 256,
  OFF_VCY   = OFF_VCX  + (size_t)B * DIM * PX,
  OFF_OTX   = OFF_VCY  + (size_t)B * DIM * PY,
  OFF_OTY   = OFF_OTX  + (size_t)B * PX * DIM,
  WS_END    = OFF_OTY  + (size_t)B * PY * DIM,
};

// ---- per-tensor dtype detection (bf16 vs f32) ----
__global__ void k_detect(const u16* x, const u16* y, const u16* wx, const u16* bx,
                         const u16* wy, const u16* by, const u16* wpx, const u16* bpx,
                         const u16* wpy, const u16* bpy, int* flags) {
  const u16* p; int n;
  switch (blockIdx.x) {
    case 0: p = x;   n = N_X;   break;
    case 1: p = y;   n = N_Y;   break;
    case 2: p = wx;  n = N_WX;  break;
    case 3: p = bx;  n = N_BX;  break;
    case 4: p = wy;  n = N_WY;  break;
    case 5: p = by;  n = N_BY;  break;
    case 6: p = wpx; n = N_WPX; break;
    case 7: p = bpx; n = N_BPX; break;
    case 8: p = wpy; n = N_WPY; break;
    default: p = bpy; n = N_BPY; break;
  }
  int ncheck = n / 2; if (ncheck > 4096) ncheck = 4096;
  int cnt = 0;
  for (int i = threadIdx.x; i < ncheck; i += 256) {
    u32 u = p[2 * i];
    if ((u & 0x7F80u) >= 0x4600u) cnt++;
  }
  __shared__ int red[256];
  red[threadIdx.x] = cnt;
  __syncthreads();
  for (int s = 128; s > 0; s >>= 1) {
    if ((int)threadIdx.x < s) red[threadIdx.x] += red[threadIdx.x + s];
    __syncthreads();
  }
  if (threadIdx.x == 0) flags[blockIdx.x] = (red[0] * 4 >= ncheck) ? 1 : 0;
}

// ---- weights/biases -> bf16 copies in ws ----
__global__ void k_convert(const void* wx, const void* bx, const void* wy, const void* by,
                          const void* wpx, const void* bpx, const void* wpy, const void* bpy,
                          u16* __restrict__ ws, const int* __restrict__ flags) {
  const void* src; size_t dstoff; int n;
  switch (blockIdx.y) {
    case 0: src = wx;  dstoff = OFF_CWX;  n = N_WX;  break;
    case 1: src = bx;  dstoff = OFF_CBX;  n = N_BX;  break;
    case 2: src = wy;  dstoff = OFF_CWY;  n = N_WY;  break;
    case 3: src = by;  dstoff = OFF_CBY;  n = N_BY;  break;
    case 4: src = wpx; dstoff = OFF_CWPX; n = N_WPX; break;
    case 5: src = bpx; dstoff = OFF_CBPX; n = N_BPX; break;
    case 6: src = wpy; dstoff = OFF_CWPY; n = N_WPY; break;
    default: src = bpy; dstoff = OFF_CBPY; n = N_BPY; break;
  }
  int e0 = (blockIdx.x * 256 + threadIdx.x) * 8;
  if (e0 >= n) return;
  u16* dst = ws + dstoff + e0;
  if (flags[blockIdx.y + 2]) {
    const float* s = (const float*)src + e0;
    float4 a = *(const float4*)s;
    float4 bq = *(const float4*)(s + 4);
    ushort4 o0, o1;
    o0.x = f2bf(a.x);  o0.y = f2bf(a.y);  o0.z = f2bf(a.z);  o0.w = f2bf(a.w);
    o1.x = f2bf(bq.x); o1.y = f2bf(bq.y); o1.z = f2bf(bq.z); o1.w = f2bf(bq.w);
    *(ushort4*)dst = o0;
    *(ushort4*)(dst + 4) = o1;
  } else {
    uint4 v = *(const uint4*)((const u16*)src + e0);
    *(uint4*)dst = v;
  }
}

// ---- input transpose + convert: src[b][c][p] -> dst[b][p][c] bf16 ----
__global__ __launch_bounds__(256) void k_xpose(
    const void* __restrict__ src, u16* __restrict__ dst,
    const int* __restrict__ flags, int fidx, int C, int P) {
  __shared__ u16 tile[32][33];
  const int tx = threadIdx.x & 31, ty = threadIdx.x >> 5;
  const int p0 = blockIdx.x * 32, c0 = blockIdx.y * 32, b = blockIdx.z;
  const bool f32in = flags[fidx] != 0;
#pragma unroll
  for (int i = 0; i < 4; i++) {
    int cl = ty * 4 + i;
    size_t sidx = ((size_t)b * C + c0 + cl) * P + p0 + tx;
    u16 v = f32in ? f2bf(((const float*)src)[sidx]) : ((const u16*)src)[sidx];
    tile[cl][tx] = v;
  }
  __syncthreads();
#pragma unroll
  for (int i = 0; i < 4; i++) {
    int pl = ty * 4 + i;
    dst[((size_t)b * P + p0 + pl) * C + c0 + tx] = tile[tx][pl];
  }
}

// ---- unified MFMA GEMM (unchanged from passing R6/R7) ----
__global__ __launch_bounds__(256) void k_mm(
    const u16* __restrict__ W, const u16* __restrict__ Xt,
    const u16* __restrict__ bias,
    u16* __restrict__ qkOut, u16* __restrict__ vOut,
    void* __restrict__ pOut, const void* __restrict__ res,
    const int* __restrict__ flags, int fidx, size_t out_off,
    int C, int P, int mode) {
  const int t = threadIdx.x;
  const int lane = t & 63, w = t >> 6;
  const int ql = lane & 15, quad = lane >> 4;
  const int p_w = blockIdx.x * 64 + (w & 1) * 32;
  const int o_w = blockIdx.y * 64 + (w >> 1) * 32;
  const int b = blockIdx.z;

  const u16* wr0 = W + (size_t)(o_w + ql) * C;
  const u16* wr1 = W + (size_t)(o_w + 16 + ql) * C;
  const u16* xr0 = Xt + ((size_t)b * P + p_w + ql) * C;
  const u16* xr1 = Xt + ((size_t)b * P + p_w + 16 + ql) * C;

  union U { uint4 u; short8 s; };
  f32x4 acc[2][2];
#pragma unroll
  for (int i = 0; i < 2; i++)
#pragma unroll
    for (int j = 0; j < 2; j++) acc[i][j] = (f32x4){0.f, 0.f, 0.f, 0.f};

#pragma unroll 4
  for (int c0 = 0; c0 < C; c0 += 32) {
    int off = c0 + quad * 8;
    U a0, a1, b0, b1;
    a0.u = *(const uint4*)&wr0[off];
    a1.u = *(const uint4*)&wr1[off];
    b0.u = *(const uint4*)&xr0[off];
    b1.u = *(const uint4*)&xr1[off];
    acc[0][0] = __builtin_amdgcn_mfma_f32_16x16x32_bf16(a0.s, b0.s, acc[0][0], 0, 0, 0);
    acc[0][1] = __builtin_amdgcn_mfma_f32_16x16x32_bf16(a0.s, b1.s, acc[0][1], 0, 0, 0);
    acc[1][0] = __builtin_amdgcn_mfma_f32_16x16x32_bf16(a1.s, b0.s, acc[1][0], 0, 0, 0);
    acc[1][1] = __builtin_amdgcn_mfma_f32_16x16x32_bf16(a1.s, b1.s, acc[1][1], 0, 0, 0);
  }

  float bs[2][4];
#pragma unroll
  for (int oi = 0; oi < 2; oi++)
#pragma unroll
    for (int r = 0; r < 4; r++)
      bs[oi][r] = bf2f(bias[o_w + oi * 16 + quad * 4 + r]);

  if (mode == 0) {
    if (blockIdx.y < 4) {
      float scale = (blockIdx.y < 2) ? GAMMA : 1.0f;
#pragma unroll
      for (int oi = 0; oi < 2; oi++)
#pragma unroll
        for (int pi = 0; pi < 2; pi++) {
          int p = p_w + pi * 16 + ql;
          int ob = o_w + oi * 16 + quad * 4;
          f32x4 a = acc[oi][pi];
          uint2 pk;
          pk.x = (u32)f2bf((a[0] + bs[oi][0]) * scale) |
                 ((u32)f2bf((a[1] + bs[oi][1]) * scale) << 16);
          pk.y = (u32)f2bf((a[2] + bs[oi][2]) * scale) |
                 ((u32)f2bf((a[3] + bs[oi][3]) * scale) << 16);
          *(uint2*)&qkOut[((size_t)b * P + p) * 256 + ob] = pk;
        }
    } else {
#pragma unroll
      for (int oi = 0; oi < 2; oi++)
#pragma unroll
        for (int pi = 0; pi < 2; pi++) {
          int p = p_w + pi * 16 + ql;
          f32x4 a = acc[oi][pi];
#pragma unroll
          for (int r = 0; r < 4; r++) {
            int o = o_w + oi * 16 + quad * 4 + r - 256;
            vOut[((size_t)b * DIM + o) * P + p] = f2bf(a[r] + bs[oi][r]);
          }
        }
    }
  } else {
    int OT = gridDim.y * 64;
    bool f32io = flags[fidx] != 0;
#pragma unroll
    for (int oi = 0; oi < 2; oi++)
#pragma unroll
      for (int pi = 0; pi < 2; pi++) {
        int p = p_w + pi * 16 + ql;
        f32x4 a = acc[oi][pi];
#pragma unroll
        for (int r = 0; r < 4; r++) {
          int o = o_w + oi * 16 + quad * 4 + r;
          size_t idx = ((size_t)b * OT + o) * P + p;
          float rv = f32io ? ((const float*)res)[idx] : bf2f(((const u16*)res)[idx]);
          float v = a[r] + bs[oi][r] + rv;
          if (f32io) ((float*)pOut)[out_off + idx] = v;
          else       ((u16*)pOut)[out_off + idx] = f2bf(v);
        }
      }
  }
}

// ---- MFMA flash attention v6: 64 queries per wave (4 Q-frags), 4-way
// in-block key split, per-wave LDS staging identical to v5 (permuted K rows,
// double-buffered gl_lds16 paced by per-wave vmcnt; ZERO in-loop barriers).
// KV L2 traffic drops 4x vs v5 (the measured bottleneck).
__global__ __launch_bounds__(256) void k_attn6(
    const u16* __restrict__ qkQ, const u16* __restrict__ qkKV,
    const u16* __restrict__ vKV, u16* __restrict__ Ot, int Pq, int Pk) {
  __shared__ __align__(16) u16 pool[16384];   // 4 waves x (K dbuf 2x2KB + V dbuf 2x2KB)
  __shared__ float mlb[2][4][64];             // [m/l][wave][query]
  const int t = threadIdx.x;
  const int lane = t & 63, w = t >> 6;
  const int ql = lane & 15, quad = lane >> 4;
  const int q0 = blockIdx.x * 64;
  const int h = blockIdx.y, b = blockIdx.z;

  union U { uint4 u; short8 s; };
  // 4 Q fragments (pre-scaled by GAMMA): B[d=quad*8+j][q=ql] for q-tiles qi
  U qf[4];
#pragma unroll
  for (int qi = 0; qi < 4; qi++)
    qf[qi].u = *(const uint4*)&qkQ[((size_t)b * Pq + q0 + qi * 16 + ql) * 256 + h * HD + quad * 8];

  const int kspan = Pk >> 2;
  const int kk0 = w * kspan;
  const int niter = kspan >> 5;   // 32-key chunks

  const u16* gK0 = qkKV + ((size_t)(b * Pk + kk0 + (lane & 31))) * 256 + 128 + h * HD + (lane >> 5) * 8;
  const u16* gK1 = gK0 + 16;
  const u16* gV0 = vKV + ((size_t)(b * DIM + h * HD + (lane & 15))) * Pk + kk0 + (lane >> 4) * 8;
  const u16* gV1 = gV0 + (size_t)16 * Pk;

  u16* wpool = pool + w * 4096;

  gl_lds16(gK0, wpool);
  gl_lds16(gK1, wpool + 512);
  gl_lds16(gV0, wpool + 2048);
  gl_lds16(gV1, wpool + 2048 + 512);

  const int f0 = ((ql >> 2) << 3) | (ql & 3);
  const int kA0 = (f0 + 32 * quad) * 8;
  const int kA1 = kA0 + 32;
  const int vA0 = 2048 + lane * 8;
  const int vA1 = 2048 + 512 + lane * 8;

  f32x4 o0[4], o1[4];
  float m_run[4], l_run[4];
#pragma unroll
  for (int qi = 0; qi < 4; qi++) {
    o0[qi] = (f32x4){0.f, 0.f, 0.f, 0.f};
    o1[qi] = (f32x4){0.f, 0.f, 0.f, 0.f};
    m_run[qi] = -1e30f; l_run[qi] = 0.f;
  }

  int buf = 0;
  for (int it = 0; it < niter; it++) {
    if (it + 1 < niter) {
      size_t go = (size_t)(it + 1) * 32;
      u16* dst = wpool + (buf ^ 1) * 1024;
      gl_lds16(gK0 + go * 256, dst);
      gl_lds16(gK1 + go * 256, dst + 512);
      gl_lds16(gV0 + go, dst + 2048);
      gl_lds16(gV1 + go, dst + 2048 + 512);
      __builtin_amdgcn_sched_barrier(0);
      __builtin_amdgcn_s_waitcnt(0x0F74);   // vmcnt <= 4: current buf landed
      __builtin_amdgcn_sched_barrier(0);
    } else {
      __builtin_amdgcn_sched_barrier(0);
      __builtin_amdgcn_s_waitcnt(0x0F70);   // vmcnt 0
      __builtin_amdgcn_sched_barrier(0);
    }
    const u16* bb = wpool + buf * 1024;
    U ka, kb, va, vb;
    ka.u = *(const uint4*)&bb[kA0];
    kb.u = *(const uint4*)&bb[kA1];
    va.u = *(const uint4*)&bb[vA0];
    vb.u = *(const uint4*)&bb[vA1];

#pragma unroll
    for (int qi = 0; qi < 4; qi++) {
      f32x4 z = {0.f, 0.f, 0.f, 0.f};
      f32x4 st0 = __builtin_amdgcn_mfma_f32_16x16x32_bf16(ka.s, qf[qi].s, z, 0, 0, 0);
      f32x4 st1 = __builtin_amdgcn_mfma_f32_16x16x32_bf16(kb.s, qf[qi].s, z, 0, 0, 0);

      float s[8] = {st0[0], st0[1], st0[2], st0[3], st1[0], st1[1], st1[2], st1[3]};
      float cm = fmaxf(fmaxf(fmaxf(s[0], s[1]), fmaxf(s[2], s[3])),
                       fmaxf(fmaxf(s[4], s[5]), fmaxf(s[6], s[7])));
      cm = fmaxf(cm, __shfl_xor(cm, 16));
      cm = fmaxf(cm, __shfl_xor(cm, 32));
      float m_new = fmaxf(m_run[qi], cm);
      float alpha = __expf(m_run[qi] - m_new);
      float p[8], ls = 0.f;
#pragma unroll
      for (int i = 0; i < 8; i++) { p[i] = __expf(s[i] - m_new); ls += p[i]; }
      ls += __shfl_xor(ls, 16);
      ls += __shfl_xor(ls, 32);
      l_run[qi] = l_run[qi] * alpha + ls;
      m_run[qi] = m_new;
#pragma unroll
      for (int r = 0; r < 4; r++) { o0[qi][r] *= alpha; o1[qi][r] *= alpha; }

      U pf;
      pf.u.x = (u32)f2bf(p[0]) | ((u32)f2bf(p[1]) << 16);
      pf.u.y = (u32)f2bf(p[2]) | ((u32)f2bf(p[3]) << 16);
      pf.u.z = (u32)f2bf(p[4]) | ((u32)f2bf(p[5]) << 16);
      pf.u.w = (u32)f2bf(p[6]) | ((u32)f2bf(p[7]) << 16);

      o0[qi] = __builtin_amdgcn_mfma_f32_16x16x32_bf16(va.s, pf.s, o0[qi], 0, 0, 0);
      o1[qi] = __builtin_amdgcn_mfma_f32_16x16x32_bf16(vb.s, pf.s, o1[qi], 0, 0, 0);
    }
    buf ^= 1;
  }

  // ---- write partials into own staging region (overlay), then merge ----
  float* Of = (float*)pool + w * 2048;   // [64 q][32 d], overlays own wpool
#pragma unroll
  for (int qi = 0; qi < 4; qi++) {
#pragma unroll
    for (int r = 0; r < 4; r++) {
      Of[(qi * 16 + ql) * 32 + quad * 4 + r] = o0[qi][r];
      Of[(qi * 16 + ql) * 32 + 16 + quad * 4 + r] = o1[qi][r];
    }
    if (quad == 0) {
      mlb[0][w][qi * 16 + ql] = m_run[qi];
      mlb[1][w][qi * 16 + ql] = l_run[qi];
    }
  }
  __syncthreads();

  const float* OfA = (const float*)pool;
#pragma unroll
  for (int k = 0; k < 8; k++) {
    int e = t + k * 256;
    int q = e >> 5, d = e & 31;
    float m0 = mlb[0][0][q], m1 = mlb[0][1][q], m2 = mlb[0][2][q], m3 = mlb[0][3][q];
    float M = fmaxf(fmaxf(m0, m1), fmaxf(m2, m3));
    float c0 = __expf(m0 - M), c1 = __expf(m1 - M), c2 = __expf(m2 - M), c3 = __expf(m3 - M);
    float lt = c0 * mlb[1][0][q] + c1 * mlb[1][1][q] + c2 * mlb[1][2][q] + c3 * mlb[1][3][q];
    int di = q * 32 + d;
    float v = c0 * OfA[di] + c1 * OfA[2048 + di] + c2 * OfA[4096 + di] + c3 * OfA[6144 + di];
    Ot[((size_t)b * Pq + q0 + q) * DIM + h * HD + d] = f2bf(v / lt);
  }
}

extern "C" void kernel_launch(void* const* d_in, const int* in_sizes, int n_in,
                              void* d_out, int out_size, void* d_ws, size_t ws_size,
                              hipStream_t stream) {
  (void)in_sizes; (void)n_in; (void)out_size; (void)ws_size;
  u16* ws = (u16*)d_ws;
  int* flags = (int*)(ws + OFF_FLAGS);
  u16* cwx  = ws + OFF_CWX;
  u16* cbx  = ws + OFF_CBX;
  u16* cwy  = ws + OFF_CWY;
  u16* cby  = ws + OFF_CBY;
  u16* cwpx = ws + OFF_CWPX;
  u16* cbpx = ws + OFF_CBPX;
  u16* cwpy = ws + OFF_CWPY;
  u16* cbpy = ws + OFF_CBPY;
  u16* xt   = ws + OFF_XT;
  u16* yt   = ws + OFF_YT;
  u16* qktx = ws + OFF_QKTX;
  u16* qkty = ws + OFF_QKTY;
  u16* vcx  = ws + OFF_VCX;
  u16* vcy  = ws + OFF_VCY;
  u16* otx  = ws + OFF_OTX;
  u16* oty  = ws + OFF_OTY;

  k_detect<<<dim3(10), 256, 0, stream>>>(
      (const u16*)d_in[0], (const u16*)d_in[1], (const u16*)d_in[2], (const u16*)d_in[3],
      (const u16*)d_in[4], (const u16*)d_in[5], (const u16*)d_in[6], (const u16*)d_in[7],
      (const u16*)d_in[8], (const u16*)d_in[9], flags);
  k_convert<<<dim3(96, 8), 256, 0, stream>>>(
      d_in[2], d_in[3], d_in[4], d_in[5], d_in[6], d_in[7], d_in[8], d_in[9], ws, flags);
  k_xpose<<<dim3(PX / 32, CX / 32, B), 256, 0, stream>>>(d_in[0], xt, flags, 0, CX, PX);
  k_xpose<<<dim3(PY / 32, CY / 32, B), 256, 0, stream>>>(d_in[1], yt, flags, 1, CY, PY);

  k_mm<<<dim3(PX / 64, 6, B), 256, 0, stream>>>(
      cwx, xt, cbx, qktx, vcx, nullptr, nullptr, flags, 0, 0, CX, PX, 0);
  k_mm<<<dim3(PY / 64, 6, B), 256, 0, stream>>>(
      cwy, yt, cby, qkty, vcy, nullptr, nullptr, flags, 0, 0, CY, PY, 0);

  k_attn6<<<dim3(PX / 64, NH, B), 256, 0, stream>>>(qktx, qkty, vcy, otx, PX, PY);
  k_attn6<<<dim3(PY / 64, NH, B), 256, 0, stream>>>(qkty, qktx, vcx, oty, PY, PX);

  k_mm<<<dim3(PX / 64, CX / 64, B), 256, 0, stream>>>(
      cwpx, otx, cbpx, nullptr, nullptr, d_out, d_in[0], flags, 0, 0, DIM, PX, 1);
  k_mm<<<dim3(PY / 64, CY / 64, B), 256, 0, stream>>>(
      cwpy, oty, cbpy, nullptr, nullptr, d_out, d_in[1], flags, 1,
      (size_t)B * CX * PX, DIM, PY, 1);
}

// Round 10
// 188.907 us; speedup vs baseline: 1.1055x; 1.1055x over previous
//
#include <hip/hip_runtime.h>
#include <hip/hip_bf16.h>
#include <cstdint>

#define B 2
#define NH 4
#define HD 32
#define DIM 128
#define CX 256
#define CY 512
#define PX 4096
#define PY 1024
#define QKV 384
#define GAMMA 0.17677669529663687f

typedef unsigned short u16;
typedef unsigned int u32;

using short8 = __attribute__((ext_vector_type(8))) short;
using f32x4  = __attribute__((ext_vector_type(4))) float;

__device__ __forceinline__ float bf2f(u32 h) {
  union { u32 u; float f; } v; v.u = (h & 0xffffu) << 16; return v.f;
}
__device__ __forceinline__ u16 f2bf(float f) {
  u32 u = __float_as_uint(f);
  u32 r = (u + 0x7fffu + ((u >> 16) & 1u)) >> 16;
  return (u16)r;
}
__device__ __forceinline__ void gl_lds16(const u16* g, u16* l) {
  __builtin_amdgcn_global_load_lds(
      (const __attribute__((address_space(1))) void*)g,
      (__attribute__((address_space(3))) void*)l, 16, 0, 0);
}

#define N_X   (B * CX * PX)
#define N_Y   (B * CY * PY)
#define N_WX  (QKV * CX)
#define N_BX  (QKV)
#define N_WY  (QKV * CY)
#define N_BY  (QKV)
#define N_WPX (CX * DIM)
#define N_BPX (CX)
#define N_WPY (CY * DIM)
#define N_BPY (CY)

// ---- workspace layout (u16 element offsets, all 16B-aligned) ----
enum : size_t {
  OFF_FLAGS = 0,
  OFF_CWX   = 32,
  OFF_CBX   = OFF_CWX  + N_WX,
  OFF_CWY   = OFF_CBX  + N_BX,
  OFF_CBY   = OFF_CWY  + N_WY,
  OFF_CWPX  = OFF_CBY  + N_BY,
  OFF_CBPX  = OFF_CWPX + N_WPX,
  OFF_CWPY  = OFF_CBPX + N_BPX,
  OFF_CBPY  = OFF_CWPY + N_WPY,
  OFF_XT    = OFF_CBPY + N_BPY,                    // [B][PX][CX]
  OFF_YT    = OFF_XT   + (size_t)B * PX * CX,      // [B][PY][CY]
  OFF_QPX   = OFF_YT   + (size_t)B * PY * CY,      // [B][NH][PX][32] packed q (scaled)
  OFF_KPX   = OFF_QPX  + (size_t)B * NH * PX * HD, // [B][NH][PX][32] packed k
  OFF_QPY   = OFF_KPX  + (size_t)B * NH * PX * HD, // [B][NH][PY][32]
  OFF_KPY   = OFF_QPY  + (size_t)B * NH * PY * HD, // [B][NH][PY][32]
  OFF_VCX   = OFF_KPY  + (size_t)B * NH * PY * HD, // [B][128][PX] channel-major v
  OFF_VCY   = OFF_VCX  + (size_t)B * DIM * PX,     // [B][128][PY]
  OFF_OTX   = OFF_VCY  + (size_t)B * DIM * PY,     // [B][PX][128] token-major attn out
  OFF_OTY   = OFF_OTX  + (size_t)B * PX * DIM,     // [B][PY][128]
  WS_END    = OFF_OTY  + (size_t)B * PY * DIM,
};

// ---- per-tensor dtype detection (bf16 vs f32) ----
__global__ void k_detect(const u16* x, const u16* y, const u16* wx, const u16* bx,
                         const u16* wy, const u16* by, const u16* wpx, const u16* bpx,
                         const u16* wpy, const u16* bpy, int* flags) {
  const u16* p; int n;
  switch (blockIdx.x) {
    case 0: p = x;   n = N_X;   break;
    case 1: p = y;   n = N_Y;   break;
    case 2: p = wx;  n = N_WX;  break;
    case 3: p = bx;  n = N_BX;  break;
    case 4: p = wy;  n = N_WY;  break;
    case 5: p = by;  n = N_BY;  break;
    case 6: p = wpx; n = N_WPX; break;
    case 7: p = bpx; n = N_BPX; break;
    case 8: p = wpy; n = N_WPY; break;
    default: p = bpy; n = N_BPY; break;
  }
  int ncheck = n / 2; if (ncheck > 4096) ncheck = 4096;
  int cnt = 0;
  for (int i = threadIdx.x; i < ncheck; i += 256) {
    u32 u = p[2 * i];
    if ((u & 0x7F80u) >= 0x4600u) cnt++;
  }
  __shared__ int red[256];
  red[threadIdx.x] = cnt;
  __syncthreads();
  for (int s = 128; s > 0; s >>= 1) {
    if ((int)threadIdx.x < s) red[threadIdx.x] += red[threadIdx.x + s];
    __syncthreads();
  }
  if (threadIdx.x == 0) flags[blockIdx.x] = (red[0] * 4 >= ncheck) ? 1 : 0;
}

// ---- weights/biases -> bf16 copies in ws ----
__global__ void k_convert(const void* wx, const void* bx, const void* wy, const void* by,
                          const void* wpx, const void* bpx, const void* wpy, const void* bpy,
                          u16* __restrict__ ws, const int* __restrict__ flags) {
  const void* src; size_t dstoff; int n;
  switch (blockIdx.y) {
    case 0: src = wx;  dstoff = OFF_CWX;  n = N_WX;  break;
    case 1: src = bx;  dstoff = OFF_CBX;  n = N_BX;  break;
    case 2: src = wy;  dstoff = OFF_CWY;  n = N_WY;  break;
    case 3: src = by;  dstoff = OFF_CBY;  n = N_BY;  break;
    case 4: src = wpx; dstoff = OFF_CWPX; n = N_WPX; break;
    case 5: src = bpx; dstoff = OFF_CBPX; n = N_BPX; break;
    case 6: src = wpy; dstoff = OFF_CWPY; n = N_WPY; break;
    default: src = bpy; dstoff = OFF_CBPY; n = N_BPY; break;
  }
  int e0 = (blockIdx.x * 256 + threadIdx.x) * 8;
  if (e0 >= n) return;
  u16* dst = ws + dstoff + e0;
  if (flags[blockIdx.y + 2]) {
    const float* s = (const float*)src + e0;
    float4 a = *(const float4*)s;
    float4 bq = *(const float4*)(s + 4);
    ushort4 o0, o1;
    o0.x = f2bf(a.x);  o0.y = f2bf(a.y);  o0.z = f2bf(a.z);  o0.w = f2bf(a.w);
    o1.x = f2bf(bq.x); o1.y = f2bf(bq.y); o1.z = f2bf(bq.z); o1.w = f2bf(bq.w);
    *(ushort4*)dst = o0;
    *(ushort4*)(dst + 4) = o1;
  } else {
    uint4 v = *(const uint4*)((const u16*)src + e0);
    *(uint4*)dst = v;
  }
}

// ---- input transpose + convert: src[b][c][p] -> dst[b][p][c] bf16 ----
__global__ __launch_bounds__(256) void k_xpose(
    const void* __restrict__ src, u16* __restrict__ dst,
    const int* __restrict__ flags, int fidx, int C, int P) {
  __shared__ u16 tile[32][33];
  const int tx = threadIdx.x & 31, ty = threadIdx.x >> 5;
  const int p0 = blockIdx.x * 32, c0 = blockIdx.y * 32, b = blockIdx.z;
  const bool f32in = flags[fidx] != 0;
#pragma unroll
  for (int i = 0; i < 4; i++) {
    int cl = ty * 4 + i;
    size_t sidx = ((size_t)b * C + c0 + cl) * P + p0 + tx;
    u16 v = f32in ? f2bf(((const float*)src)[sidx]) : ((const u16*)src)[sidx];
    tile[cl][tx] = v;
  }
  __syncthreads();
#pragma unroll
  for (int i = 0; i < 4; i++) {
    int pl = ty * 4 + i;
    dst[((size_t)b * P + p0 + pl) * C + c0 + tx] = tile[tx][pl];
  }
}

// ---- unified MFMA GEMM. mode 0 (qkv): q -> Qp packed per-head (scaled),
// k -> Kp packed per-head, v -> channel-major Vc. mode 1 (proj): +res -> out.
__global__ __launch_bounds__(256) void k_mm(
    const u16* __restrict__ W, const u16* __restrict__ Xt,
    const u16* __restrict__ bias,
    u16* __restrict__ qpOut, u16* __restrict__ kpOut, u16* __restrict__ vOut,
    void* __restrict__ pOut, const void* __restrict__ res,
    const int* __restrict__ flags, int fidx, size_t out_off,
    int C, int P, int mode) {
  const int t = threadIdx.x;
  const int lane = t & 63, w = t >> 6;
  const int ql = lane & 15, quad = lane >> 4;
  const int p_w = blockIdx.x * 64 + (w & 1) * 32;
  const int o_w = blockIdx.y * 64 + (w >> 1) * 32;
  const int b = blockIdx.z;

  const u16* wr0 = W + (size_t)(o_w + ql) * C;
  const u16* wr1 = W + (size_t)(o_w + 16 + ql) * C;
  const u16* xr0 = Xt + ((size_t)b * P + p_w + ql) * C;
  const u16* xr1 = Xt + ((size_t)b * P + p_w + 16 + ql) * C;

  union U { uint4 u; short8 s; };
  f32x4 acc[2][2];
#pragma unroll
  for (int i = 0; i < 2; i++)
#pragma unroll
    for (int j = 0; j < 2; j++) acc[i][j] = (f32x4){0.f, 0.f, 0.f, 0.f};

#pragma unroll 4
  for (int c0 = 0; c0 < C; c0 += 32) {
    int off = c0 + quad * 8;
    U a0, a1, b0, b1;
    a0.u = *(const uint4*)&wr0[off];
    a1.u = *(const uint4*)&wr1[off];
    b0.u = *(const uint4*)&xr0[off];
    b1.u = *(const uint4*)&xr1[off];
    acc[0][0] = __builtin_amdgcn_mfma_f32_16x16x32_bf16(a0.s, b0.s, acc[0][0], 0, 0, 0);
    acc[0][1] = __builtin_amdgcn_mfma_f32_16x16x32_bf16(a0.s, b1.s, acc[0][1], 0, 0, 0);
    acc[1][0] = __builtin_amdgcn_mfma_f32_16x16x32_bf16(a1.s, b0.s, acc[1][0], 0, 0, 0);
    acc[1][1] = __builtin_amdgcn_mfma_f32_16x16x32_bf16(a1.s, b1.s, acc[1][1], 0, 0, 0);
  }

  float bs[2][4];
#pragma unroll
  for (int oi = 0; oi < 2; oi++)
#pragma unroll
    for (int r = 0; r < 4; r++)
      bs[oi][r] = bf2f(bias[o_w + oi * 16 + quad * 4 + r]);

  if (mode == 0) {
    if (blockIdx.y < 4) {
      bool isq = blockIdx.y < 2;
      float scale = isq ? GAMMA : 1.0f;
      u16* dstT = isq ? qpOut : kpOut;
#pragma unroll
      for (int oi = 0; oi < 2; oi++)
#pragma unroll
        for (int pi = 0; pi < 2; pi++) {
          int p = p_w + pi * 16 + ql;
          int o = o_w + oi * 16 + quad * 4 - (isq ? 0 : 128);
          int hh = o >> 5, d = o & 31;
          f32x4 a = acc[oi][pi];
          uint2 pk;
          pk.x = (u32)f2bf((a[0] + bs[oi][0]) * scale) |
                 ((u32)f2bf((a[1] + bs[oi][1]) * scale) << 16);
          pk.y = (u32)f2bf((a[2] + bs[oi][2]) * scale) |
                 ((u32)f2bf((a[3] + bs[oi][3]) * scale) << 16);
          *(uint2*)&dstT[((size_t)(b * NH + hh) * P + p) * HD + d] = pk;
        }
    } else {
#pragma unroll
      for (int oi = 0; oi < 2; oi++)
#pragma unroll
        for (int pi = 0; pi < 2; pi++) {
          int p = p_w + pi * 16 + ql;
          f32x4 a = acc[oi][pi];
#pragma unroll
          for (int r = 0; r < 4; r++) {
            int o = o_w + oi * 16 + quad * 4 + r - 256;
            vOut[((size_t)b * DIM + o) * P + p] = f2bf(a[r] + bs[oi][r]);
          }
        }
    }
  } else {
    int OT = gridDim.y * 64;
    bool f32io = flags[fidx] != 0;
#pragma unroll
    for (int oi = 0; oi < 2; oi++)
#pragma unroll
      for (int pi = 0; pi < 2; pi++) {
        int p = p_w + pi * 16 + ql;
        f32x4 a = acc[oi][pi];
#pragma unroll
        for (int r = 0; r < 4; r++) {
          int o = o_w + oi * 16 + quad * 4 + r;
          size_t idx = ((size_t)b * OT + o) * P + p;
          float rv = f32io ? ((const float*)res)[idx] : bf2f(((const u16*)res)[idx]);
          float v = a[r] + bs[oi][r] + rv;
          if (f32io) ((float*)pOut)[out_off + idx] = v;
          else       ((u16*)pOut)[out_off + idx] = f2bf(v);
        }
      }
  }
}

// ---- MFMA flash attention v7b: packed per-head Q/K (streaming HBM lines),
// NQF 16-query-fragments per wave, 4-way in-block key split, permuted-K LDS
// staging (QK^T C-layout == PV B-layout; no in-loop barriers), dbuf paced by
// per-wave vmcnt. FIX vs v7: merge overlay based at wave's OWN staging region
// (pool + w*4096 u16) for ANY NQF — v7's float-offset math collided wave 1's
// partials into wave 0's live V staging for NQF=2 (the y-direction NaN).
template <int NQF>
__global__ __launch_bounds__(256) void k_attn7(
    const u16* __restrict__ Qp, const u16* __restrict__ Kp,
    const u16* __restrict__ Vc, u16* __restrict__ Ot, int Pq, int Pk) {
  __shared__ __align__(16) u16 pool[16384];   // 4 waves x (K dbuf 2x2KB + V dbuf 2x2KB)
  __shared__ float mlb[2][4][64];
  const int t = threadIdx.x;
  const int lane = t & 63, w = t >> 6;
  const int ql = lane & 15, quad = lane >> 4;
  const int q0 = blockIdx.x * (NQF * 16);
  const int h = blockIdx.y, b = blockIdx.z;

  union U { uint4 u; short8 s; };
  U qf[NQF];
#pragma unroll
  for (int qi = 0; qi < NQF; qi++)
    qf[qi].u = *(const uint4*)&Qp[((size_t)(b * NH + h) * Pq + q0 + qi * 16 + ql) * HD + quad * 8];

  const int kspan = Pk >> 2;
  const int kk0 = w * kspan;
  const int niter = kspan >> 5;

  const u16* gK0 = Kp + ((size_t)(b * NH + h) * Pk + kk0 + (lane & 31)) * HD + (lane >> 5) * 8;
  const u16* gK1 = gK0 + 16;
  const u16* gV0 = Vc + ((size_t)(b * DIM + h * HD + (lane & 15))) * Pk + kk0 + (lane >> 4) * 8;
  const u16* gV1 = gV0 + (size_t)16 * Pk;

  u16* wpool = pool + w * 4096;

  gl_lds16(gK0, wpool);
  gl_lds16(gK1, wpool + 512);
  gl_lds16(gV0, wpool + 2048);
  gl_lds16(gV1, wpool + 2048 + 512);

  const int f0 = ((ql >> 2) << 3) | (ql & 3);
  const int kA0 = (f0 + 32 * quad) * 8;
  const int kA1 = kA0 + 32;
  const int vA0 = 2048 + lane * 8;
  const int vA1 = 2048 + 512 + lane * 8;

  f32x4 o0[NQF], o1[NQF];
  float m_run[NQF], l_run[NQF];
#pragma unroll
  for (int qi = 0; qi < NQF; qi++) {
    o0[qi] = (f32x4){0.f, 0.f, 0.f, 0.f};
    o1[qi] = (f32x4){0.f, 0.f, 0.f, 0.f};
    m_run[qi] = -1e30f; l_run[qi] = 0.f;
  }

  int buf = 0;
  for (int it = 0; it < niter; it++) {
    if (it + 1 < niter) {
      size_t go = (size_t)(it + 1) * 32;
      u16* dst = wpool + (buf ^ 1) * 1024;
      gl_lds16(gK0 + go * HD, dst);
      gl_lds16(gK1 + go * HD, dst + 512);
      gl_lds16(gV0 + go, dst + 2048);
      gl_lds16(gV1 + go, dst + 2048 + 512);
      __builtin_amdgcn_sched_barrier(0);
      __builtin_amdgcn_s_waitcnt(0x0F74);   // vmcnt <= 4
      __builtin_amdgcn_sched_barrier(0);
    } else {
      __builtin_amdgcn_sched_barrier(0);
      __builtin_amdgcn_s_waitcnt(0x0F70);   // vmcnt 0
      __builtin_amdgcn_sched_barrier(0);
    }
    const u16* bb = wpool + buf * 1024;
    U ka, kb, va, vb;
    ka.u = *(const uint4*)&bb[kA0];
    kb.u = *(const uint4*)&bb[kA1];
    va.u = *(const uint4*)&bb[vA0];
    vb.u = *(const uint4*)&bb[vA1];

#pragma unroll
    for (int qi = 0; qi < NQF; qi++) {
      f32x4 z = {0.f, 0.f, 0.f, 0.f};
      f32x4 st0 = __builtin_amdgcn_mfma_f32_16x16x32_bf16(ka.s, qf[qi].s, z, 0, 0, 0);
      f32x4 st1 = __builtin_amdgcn_mfma_f32_16x16x32_bf16(kb.s, qf[qi].s, z, 0, 0, 0);

      float s[8] = {st0[0], st0[1], st0[2], st0[3], st1[0], st1[1], st1[2], st1[3]};
      float cm = fmaxf(fmaxf(fmaxf(s[0], s[1]), fmaxf(s[2], s[3])),
                       fmaxf(fmaxf(s[4], s[5]), fmaxf(s[6], s[7])));
      cm = fmaxf(cm, __shfl_xor(cm, 16));
      cm = fmaxf(cm, __shfl_xor(cm, 32));
      float m_new = fmaxf(m_run[qi], cm);
      float alpha = __expf(m_run[qi] - m_new);
      float p[8], ls = 0.f;
#pragma unroll
      for (int i = 0; i < 8; i++) { p[i] = __expf(s[i] - m_new); ls += p[i]; }
      ls += __shfl_xor(ls, 16);
      ls += __shfl_xor(ls, 32);
      l_run[qi] = l_run[qi] * alpha + ls;
      m_run[qi] = m_new;
#pragma unroll
      for (int r = 0; r < 4; r++) { o0[qi][r] *= alpha; o1[qi][r] *= alpha; }

      U pf;
      pf.u.x = (u32)f2bf(p[0]) | ((u32)f2bf(p[1]) << 16);
      pf.u.y = (u32)f2bf(p[2]) | ((u32)f2bf(p[3]) << 16);
      pf.u.z = (u32)f2bf(p[4]) | ((u32)f2bf(p[5]) << 16);
      pf.u.w = (u32)f2bf(p[6]) | ((u32)f2bf(p[7]) << 16);

      o0[qi] = __builtin_amdgcn_mfma_f32_16x16x32_bf16(va.s, pf.s, o0[qi], 0, 0, 0);
      o1[qi] = __builtin_amdgcn_mfma_f32_16x16x32_bf16(vb.s, pf.s, o1[qi], 0, 0, 0);
    }
    buf ^= 1;
  }

  // ---- merge 4 wave-partials via LDS. Each wave's overlay sits in its OWN
  // 8KB staging region (pool + w*4096 u16) — safe without inter-wave sync.
  float* Of = (float*)(pool + (size_t)w * 4096);   // [NQF*16 q][32 d]
#pragma unroll
  for (int qi = 0; qi < NQF; qi++) {
#pragma unroll
    for (int r = 0; r < 4; r++) {
      Of[(qi * 16 + ql) * 32 + quad * 4 + r] = o0[qi][r];
      Of[(qi * 16 + ql) * 32 + 16 + quad * 4 + r] = o1[qi][r];
    }
    if (quad == 0) {
      mlb[0][w][qi * 16 + ql] = m_run[qi];
      mlb[1][w][qi * 16 + ql] = l_run[qi];
    }
  }
  __syncthreads();

  const float* OfA = (const float*)pool;   // wave w partials at OfA[w*2048 + q*32 + d]
#pragma unroll
  for (int k = 0; k < NQF * 2; k++) {
    int e = t + k * 256;
    int q = e >> 5, d = e & 31;
    float m0 = mlb[0][0][q], m1 = mlb[0][1][q], m2 = mlb[0][2][q], m3 = mlb[0][3][q];
    float M = fmaxf(fmaxf(m0, m1), fmaxf(m2, m3));
    float c0 = __expf(m0 - M), c1 = __expf(m1 - M), c2 = __expf(m2 - M), c3 = __expf(m3 - M);
    float lt = c0 * mlb[1][0][q] + c1 * mlb[1][1][q] + c2 * mlb[1][2][q] + c3 * mlb[1][3][q];
    int di = q * 32 + d;
    float v = c0 * OfA[di] + c1 * OfA[2048 + di] +
              c2 * OfA[4096 + di] + c3 * OfA[6144 + di];
    Ot[((size_t)b * Pq + q0 + q) * DIM + h * HD + d] = f2bf(v / lt);
  }
}

extern "C" void kernel_launch(void* const* d_in, const int* in_sizes, int n_in,
                              void* d_out, int out_size, void* d_ws, size_t ws_size,
                              hipStream_t stream) {
  (void)in_sizes; (void)n_in; (void)out_size; (void)ws_size;
  u16* ws = (u16*)d_ws;
  int* flags = (int*)(ws + OFF_FLAGS);
  u16* cwx  = ws + OFF_CWX;
  u16* cbx  = ws + OFF_CBX;
  u16* cwy  = ws + OFF_CWY;
  u16* cby  = ws + OFF_CBY;
  u16* cwpx = ws + OFF_CWPX;
  u16* cbpx = ws + OFF_CBPX;
  u16* cwpy = ws + OFF_CWPY;
  u16* cbpy = ws + OFF_CBPY;
  u16* xt   = ws + OFF_XT;
  u16* yt   = ws + OFF_YT;
  u16* qpx  = ws + OFF_QPX;
  u16* kpx  = ws + OFF_KPX;
  u16* qpy  = ws + OFF_QPY;
  u16* kpy  = ws + OFF_KPY;
  u16* vcx  = ws + OFF_VCX;
  u16* vcy  = ws + OFF_VCY;
  u16* otx  = ws + OFF_OTX;
  u16* oty  = ws + OFF_OTY;

  k_detect<<<dim3(10), 256, 0, stream>>>(
      (const u16*)d_in[0], (const u16*)d_in[1], (const u16*)d_in[2], (const u16*)d_in[3],
      (const u16*)d_in[4], (const u16*)d_in[5], (const u16*)d_in[6], (const u16*)d_in[7],
      (const u16*)d_in[8], (const u16*)d_in[9], flags);
  k_convert<<<dim3(96, 8), 256, 0, stream>>>(
      d_in[2], d_in[3], d_in[4], d_in[5], d_in[6], d_in[7], d_in[8], d_in[9], ws, flags);
  k_xpose<<<dim3(PX / 32, CX / 32, B), 256, 0, stream>>>(d_in[0], xt, flags, 0, CX, PX);
  k_xpose<<<dim3(PY / 32, CY / 32, B), 256, 0, stream>>>(d_in[1], yt, flags, 1, CY, PY);

  k_mm<<<dim3(PX / 64, 6, B), 256, 0, stream>>>(
      cwx, xt, cbx, qpx, kpx, vcx, nullptr, nullptr, flags, 0, 0, CX, PX, 0);
  k_mm<<<dim3(PY / 64, 6, B), 256, 0, stream>>>(
      cwy, yt, cby, qpy, kpy, vcy, nullptr, nullptr, flags, 0, 0, CY, PY, 0);

  k_attn7<4><<<dim3(PX / 64, NH, B), 256, 0, stream>>>(qpx, kpy, vcy, otx, PX, PY);
  k_attn7<2><<<dim3(PY / 32, NH, B), 256, 0, stream>>>(qpy, kpx, vcx, oty, PY, PX);

  k_mm<<<dim3(PX / 64, CX / 64, B), 256, 0, stream>>>(
      cwpx, otx, cbpx, nullptr, nullptr, nullptr, d_out, d_in[0], flags, 0, 0, DIM, PX, 1);
  k_mm<<<dim3(PY / 64, CY / 64, B), 256, 0, stream>>>(
      cwpy, oty, cbpy, nullptr, nullptr, nullptr, d_out, d_in[1], flags, 1,
      (size_t)B * CX * PX, DIM, PY, 1);
}

// Round 11
// 163.017 us; speedup vs baseline: 1.2811x; 1.1588x over previous
//
#include <hip/hip_runtime.h>
#include <hip/hip_bf16.h>
#include <cstdint>

#define B 2
#define NH 4
#define HD 32
#define DIM 128
#define CX 256
#define CY 512
#define PX 4096
#define PY 1024
#define QKV 384
#define GAMMA 0.17677669529663687f

typedef unsigned short u16;
typedef unsigned int u32;

using short8 = __attribute__((ext_vector_type(8))) short;
using f32x4  = __attribute__((ext_vector_type(4))) float;

__device__ __forceinline__ float bf2f(u32 h) {
  union { u32 u; float f; } v; v.u = (h & 0xffffu) << 16; return v.f;
}
__device__ __forceinline__ u16 f2bf(float f) {
  u32 u = __float_as_uint(f);
  u32 r = (u + 0x7fffu + ((u >> 16) & 1u)) >> 16;
  return (u16)r;
}
__device__ __forceinline__ void gl_lds16(const u16* g, u16* l) {
  __builtin_amdgcn_global_load_lds(
      (const __attribute__((address_space(1))) void*)g,
      (__attribute__((address_space(3))) void*)l, 16, 0, 0);
}
// per-wave dtype sample: f32 buffers have ~45% huge-exponent u16 patterns at
// even indices; bf16 data (|v|<=8) has none. 64 samples -> P[miss] ~ 3e-17.
__device__ __forceinline__ bool is_f32(const void* src) {
  u32 u = ((const u16*)src)[2 * (threadIdx.x & 63)];
  return __ballot((u & 0x7F80u) >= 0x4600u) != 0ull;
}

#define N_X   (B * CX * PX)
#define N_Y   (B * CY * PY)
#define N_WX  (QKV * CX)
#define N_BX  (QKV)
#define N_WY  (QKV * CY)
#define N_BY  (QKV)
#define N_WPX (CX * DIM)
#define N_BPX (CX)
#define N_WPY (CY * DIM)
#define N_BPY (CY)

// ---- workspace layout (u16 element offsets, all 16B-aligned) ----
enum : size_t {
  OFF_CWX   = 0,
  OFF_CBX   = OFF_CWX  + N_WX,
  OFF_CWY   = OFF_CBX  + N_BX,
  OFF_CBY   = OFF_CWY  + N_WY,
  OFF_CWPX  = OFF_CBY  + N_BY,
  OFF_CBPX  = OFF_CWPX + N_WPX,
  OFF_CWPY  = OFF_CBPX + N_BPX,
  OFF_CBPY  = OFF_CWPY + N_WPY,
  OFF_XT    = OFF_CBPY + N_BPY,                    // [B][PX][CX]
  OFF_YT    = OFF_XT   + (size_t)B * PX * CX,      // [B][PY][CY]
  OFF_QPX   = OFF_YT   + (size_t)B * PY * CY,      // [B][NH][PX][32] q packed (scaled)
  OFF_KPX   = OFF_QPX  + (size_t)B * NH * PX * HD, // [B][NH][PX][32]
  OFF_QPY   = OFF_KPX  + (size_t)B * NH * PX * HD, // [B][NH][PY][32]
  OFF_KPY   = OFF_QPY  + (size_t)B * NH * PY * HD, // [B][NH][PY][32]
  OFF_VCX   = OFF_KPY  + (size_t)B * NH * PY * HD, // [B][128][PX]
  OFF_VCY   = OFF_VCX  + (size_t)B * DIM * PX,     // [B][128][PY]
  OFF_OTX   = OFF_VCY  + (size_t)B * DIM * PY,     // [B][PX][128]
  OFF_OTY   = OFF_OTX  + (size_t)B * PX * DIM,     // [B][PY][128]
  WS_END    = OFF_OTY  + (size_t)B * PY * DIM,
};

// ==== k_prep: fused dtype-detect + weight/bias convert + input transposes ====
// grid.x = 2048 (xpose-x) + 1024 (xpose-y) + 196 (weight copy) = 3268
#define XPX_BLKS 2048
#define XPY_BLKS 1024
__global__ __launch_bounds__(256) void k_prep(
    const void* x, const void* y, const void* wx, const void* bx,
    const void* wy, const void* by, const void* wpx, const void* bpx,
    const void* wpy, const void* bpy, u16* __restrict__ ws) {
  const int id = blockIdx.x;
  if (id < XPX_BLKS + XPY_BLKS) {
    // ---- input transpose + convert: src[b][c][p] -> dst[b][p][c] bf16 ----
    __shared__ u16 tile[32][33];
    const void* src; u16* dst; int C, P, p_t, c_t, b;
    if (id < XPX_BLKS) {
      src = x; dst = ws + OFF_XT; C = CX; P = PX;
      p_t = id & 127; c_t = (id >> 7) & 7; b = id >> 10;
    } else {
      int id2 = id - XPX_BLKS;
      src = y; dst = ws + OFF_YT; C = CY; P = PY;
      p_t = id2 & 31; c_t = (id2 >> 5) & 15; b = id2 >> 9;
    }
    const bool f32in = is_f32(src);
    const int tx = threadIdx.x & 31, ty = threadIdx.x >> 5;
    const int p0 = p_t * 32, c0 = c_t * 32;
#pragma unroll
    for (int i = 0; i < 4; i++) {
      int cl = ty * 4 + i;
      size_t sidx = ((size_t)b * C + c0 + cl) * P + p0 + tx;
      u16 v = f32in ? f2bf(((const float*)src)[sidx]) : ((const u16*)src)[sidx];
      tile[cl][tx] = v;
    }
    __syncthreads();
#pragma unroll
    for (int i = 0; i < 4; i++) {
      int pl = ty * 4 + i;
      dst[((size_t)b * P + p0 + pl) * C + c0 + tx] = tile[tx][pl];
    }
  } else {
    // ---- weight/bias -> bf16 copies. fixed block counts per tensor ----
    int wid = id - (XPX_BLKS + XPY_BLKS);
    const void* src; size_t dstoff; int n, base;
    if      (wid < 48)  { src = wx;  dstoff = OFF_CWX;  n = N_WX;  base = 0; }
    else if (wid < 49)  { src = bx;  dstoff = OFF_CBX;  n = N_BX;  base = 48; }
    else if (wid < 145) { src = wy;  dstoff = OFF_CWY;  n = N_WY;  base = 49; }
    else if (wid < 146) { src = by;  dstoff = OFF_CBY;  n = N_BY;  base = 145; }
    else if (wid < 162) { src = wpx; dstoff = OFF_CWPX; n = N_WPX; base = 146; }
    else if (wid < 163) { src = bpx; dstoff = OFF_CBPX; n = N_BPX; base = 162; }
    else if (wid < 195) { src = wpy; dstoff = OFF_CWPY; n = N_WPY; base = 163; }
    else                { src = bpy; dstoff = OFF_CBPY; n = N_BPY; base = 195; }
    const bool f32in = is_f32(src);
    int e0 = (wid - base) * 2048 + threadIdx.x * 8;
    if (e0 >= n) return;
    u16* dst = ws + dstoff + e0;
    if (f32in) {
      const float* s = (const float*)src + e0;
      float4 a = *(const float4*)s;
      float4 bq = *(const float4*)(s + 4);
      ushort4 o0, o1;
      o0.x = f2bf(a.x);  o0.y = f2bf(a.y);  o0.z = f2bf(a.z);  o0.w = f2bf(a.w);
      o1.x = f2bf(bq.x); o1.y = f2bf(bq.y); o1.z = f2bf(bq.z); o1.w = f2bf(bq.w);
      *(ushort4*)dst = o0;
      *(ushort4*)(dst + 4) = o1;
    } else {
      uint4 v = *(const uint4*)((const u16*)src + e0);
      *(uint4*)dst = v;
    }
  }
}

// ==== k_qkv: fused x+y qkv GEMMs (MFMA, no LDS) ====
// grid (80, 6, B): bx<64 -> x (P=PX,C=CX), else y (P=PY,C=CY).
// blockIdx.y<2: q -> Qp packed per-head (GAMMA folded); <4: k -> Kp; else v -> Vc.
__global__ __launch_bounds__(256) void k_qkv(u16* __restrict__ ws) {
  const int t = threadIdx.x;
  const int lane = t & 63, w = t >> 6;
  const int ql = lane & 15, quad = lane >> 4;
  const int b = blockIdx.z;

  const u16 *W, *Xt, *bias; u16 *qp, *kp, *vc; int C, P, pxb;
  if (blockIdx.x < 64) {
    W = ws + OFF_CWX; Xt = ws + OFF_XT; bias = ws + OFF_CBX;
    qp = ws + OFF_QPX; kp = ws + OFF_KPX; vc = ws + OFF_VCX;
    C = CX; P = PX; pxb = blockIdx.x;
  } else {
    W = ws + OFF_CWY; Xt = ws + OFF_YT; bias = ws + OFF_CBY;
    qp = ws + OFF_QPY; kp = ws + OFF_KPY; vc = ws + OFF_VCY;
    C = CY; P = PY; pxb = blockIdx.x - 64;
  }
  const int p_w = pxb * 64 + (w & 1) * 32;
  const int o_w = blockIdx.y * 64 + (w >> 1) * 32;

  const u16* wr0 = W + (size_t)(o_w + ql) * C;
  const u16* wr1 = W + (size_t)(o_w + 16 + ql) * C;
  const u16* xr0 = Xt + ((size_t)b * P + p_w + ql) * C;
  const u16* xr1 = Xt + ((size_t)b * P + p_w + 16 + ql) * C;

  union U { uint4 u; short8 s; };
  f32x4 acc[2][2];
#pragma unroll
  for (int i = 0; i < 2; i++)
#pragma unroll
    for (int j = 0; j < 2; j++) acc[i][j] = (f32x4){0.f, 0.f, 0.f, 0.f};

#pragma unroll 4
  for (int c0 = 0; c0 < C; c0 += 32) {
    int off = c0 + quad * 8;
    U a0, a1, b0, b1;
    a0.u = *(const uint4*)&wr0[off];
    a1.u = *(const uint4*)&wr1[off];
    b0.u = *(const uint4*)&xr0[off];
    b1.u = *(const uint4*)&xr1[off];
    acc[0][0] = __builtin_amdgcn_mfma_f32_16x16x32_bf16(a0.s, b0.s, acc[0][0], 0, 0, 0);
    acc[0][1] = __builtin_amdgcn_mfma_f32_16x16x32_bf16(a0.s, b1.s, acc[0][1], 0, 0, 0);
    acc[1][0] = __builtin_amdgcn_mfma_f32_16x16x32_bf16(a1.s, b0.s, acc[1][0], 0, 0, 0);
    acc[1][1] = __builtin_amdgcn_mfma_f32_16x16x32_bf16(a1.s, b1.s, acc[1][1], 0, 0, 0);
  }

  float bs[2][4];
#pragma unroll
  for (int oi = 0; oi < 2; oi++)
#pragma unroll
    for (int r = 0; r < 4; r++)
      bs[oi][r] = bf2f(bias[o_w + oi * 16 + quad * 4 + r]);

  if (blockIdx.y < 4) {
    bool isq = blockIdx.y < 2;
    float scale = isq ? GAMMA : 1.0f;
    u16* dstT = isq ? qp : kp;
#pragma unroll
    for (int oi = 0; oi < 2; oi++)
#pragma unroll
      for (int pi = 0; pi < 2; pi++) {
        int p = p_w + pi * 16 + ql;
        int o = o_w + oi * 16 + quad * 4 - (isq ? 0 : 128);
        int hh = o >> 5, d = o & 31;
        f32x4 a = acc[oi][pi];
        uint2 pk;
        pk.x = (u32)f2bf((a[0] + bs[oi][0]) * scale) |
               ((u32)f2bf((a[1] + bs[oi][1]) * scale) << 16);
        pk.y = (u32)f2bf((a[2] + bs[oi][2]) * scale) |
               ((u32)f2bf((a[3] + bs[oi][3]) * scale) << 16);
        *(uint2*)&dstT[((size_t)(b * NH + hh) * P + p) * HD + d] = pk;
      }
  } else {
#pragma unroll
    for (int oi = 0; oi < 2; oi++)
#pragma unroll
      for (int pi = 0; pi < 2; pi++) {
        int p = p_w + pi * 16 + ql;
        f32x4 a = acc[oi][pi];
#pragma unroll
        for (int r = 0; r < 4; r++) {
          int o = o_w + oi * 16 + quad * 4 + r - 256;
          vc[((size_t)b * DIM + o) * P + p] = f2bf(a[r] + bs[oi][r]);
        }
      }
  }
}

// ==== attention core (verified R10 machinery, unchanged) ====
template <int NQF>
__device__ __forceinline__ void attn_core(
    const u16* __restrict__ Qp, const u16* __restrict__ Kp,
    const u16* __restrict__ Vc, u16* __restrict__ Ot, int Pq, int Pk,
    int q0, int h, int b, u16* pool, float (*mlb)[4][64]) {
  const int t = threadIdx.x;
  const int lane = t & 63, w = t >> 6;
  const int ql = lane & 15, quad = lane >> 4;

  union U { uint4 u; short8 s; };
  U qf[NQF];
#pragma unroll
  for (int qi = 0; qi < NQF; qi++)
    qf[qi].u = *(const uint4*)&Qp[((size_t)(b * NH + h) * Pq + q0 + qi * 16 + ql) * HD + quad * 8];

  const int kspan = Pk >> 2;
  const int kk0 = w * kspan;
  const int niter = kspan >> 5;

  const u16* gK0 = Kp + ((size_t)(b * NH + h) * Pk + kk0 + (lane & 31)) * HD + (lane >> 5) * 8;
  const u16* gK1 = gK0 + 16;
  const u16* gV0 = Vc + ((size_t)(b * DIM + h * HD + (lane & 15))) * Pk + kk0 + (lane >> 4) * 8;
  const u16* gV1 = gV0 + (size_t)16 * Pk;

  u16* wpool = pool + w * 4096;

  gl_lds16(gK0, wpool);
  gl_lds16(gK1, wpool + 512);
  gl_lds16(gV0, wpool + 2048);
  gl_lds16(gV1, wpool + 2048 + 512);

  const int f0 = ((ql >> 2) << 3) | (ql & 3);
  const int kA0 = (f0 + 32 * quad) * 8;
  const int kA1 = kA0 + 32;
  const int vA0 = 2048 + lane * 8;
  const int vA1 = 2048 + 512 + lane * 8;

  f32x4 o0[NQF], o1[NQF];
  float m_run[NQF], l_run[NQF];
#pragma unroll
  for (int qi = 0; qi < NQF; qi++) {
    o0[qi] = (f32x4){0.f, 0.f, 0.f, 0.f};
    o1[qi] = (f32x4){0.f, 0.f, 0.f, 0.f};
    m_run[qi] = -1e30f; l_run[qi] = 0.f;
  }

  int buf = 0;
  for (int it = 0; it < niter; it++) {
    if (it + 1 < niter) {
      size_t go = (size_t)(it + 1) * 32;
      u16* dst = wpool + (buf ^ 1) * 1024;
      gl_lds16(gK0 + go * HD, dst);
      gl_lds16(gK1 + go * HD, dst + 512);
      gl_lds16(gV0 + go, dst + 2048);
      gl_lds16(gV1 + go, dst + 2048 + 512);
      __builtin_amdgcn_sched_barrier(0);
      __builtin_amdgcn_s_waitcnt(0x0F74);   // vmcnt <= 4
      __builtin_amdgcn_sched_barrier(0);
    } else {
      __builtin_amdgcn_sched_barrier(0);
      __builtin_amdgcn_s_waitcnt(0x0F70);   // vmcnt 0
      __builtin_amdgcn_sched_barrier(0);
    }
    const u16* bb = wpool + buf * 1024;
    U ka, kb, va, vb;
    ka.u = *(const uint4*)&bb[kA0];
    kb.u = *(const uint4*)&bb[kA1];
    va.u = *(const uint4*)&bb[vA0];
    vb.u = *(const uint4*)&bb[vA1];

#pragma unroll
    for (int qi = 0; qi < NQF; qi++) {
      f32x4 z = {0.f, 0.f, 0.f, 0.f};
      f32x4 st0 = __builtin_amdgcn_mfma_f32_16x16x32_bf16(ka.s, qf[qi].s, z, 0, 0, 0);
      f32x4 st1 = __builtin_amdgcn_mfma_f32_16x16x32_bf16(kb.s, qf[qi].s, z, 0, 0, 0);

      float s[8] = {st0[0], st0[1], st0[2], st0[3], st1[0], st1[1], st1[2], st1[3]};
      float cm = fmaxf(fmaxf(fmaxf(s[0], s[1]), fmaxf(s[2], s[3])),
                       fmaxf(fmaxf(s[4], s[5]), fmaxf(s[6], s[7])));
      cm = fmaxf(cm, __shfl_xor(cm, 16));
      cm = fmaxf(cm, __shfl_xor(cm, 32));
      float m_new = fmaxf(m_run[qi], cm);
      float alpha = __expf(m_run[qi] - m_new);
      float p[8], ls = 0.f;
#pragma unroll
      for (int i = 0; i < 8; i++) { p[i] = __expf(s[i] - m_new); ls += p[i]; }
      ls += __shfl_xor(ls, 16);
      ls += __shfl_xor(ls, 32);
      l_run[qi] = l_run[qi] * alpha + ls;
      m_run[qi] = m_new;
#pragma unroll
      for (int r = 0; r < 4; r++) { o0[qi][r] *= alpha; o1[qi][r] *= alpha; }

      U pf;
      pf.u.x = (u32)f2bf(p[0]) | ((u32)f2bf(p[1]) << 16);
      pf.u.y = (u32)f2bf(p[2]) | ((u32)f2bf(p[3]) << 16);
      pf.u.z = (u32)f2bf(p[4]) | ((u32)f2bf(p[5]) << 16);
      pf.u.w = (u32)f2bf(p[6]) | ((u32)f2bf(p[7]) << 16);

      o0[qi] = __builtin_amdgcn_mfma_f32_16x16x32_bf16(va.s, pf.s, o0[qi], 0, 0, 0);
      o1[qi] = __builtin_amdgcn_mfma_f32_16x16x32_bf16(vb.s, pf.s, o1[qi], 0, 0, 0);
    }
    buf ^= 1;
  }

  // merge 4 wave-partials: each wave's overlay in its OWN 8KB staging region
  float* Of = (float*)(pool + (size_t)w * 4096);
#pragma unroll
  for (int qi = 0; qi < NQF; qi++) {
#pragma unroll
    for (int r = 0; r < 4; r++) {
      Of[(qi * 16 + ql) * 32 + quad * 4 + r] = o0[qi][r];
      Of[(qi * 16 + ql) * 32 + 16 + quad * 4 + r] = o1[qi][r];
    }
    if (quad == 0) {
      mlb[0][w][qi * 16 + ql] = m_run[qi];
      mlb[1][w][qi * 16 + ql] = l_run[qi];
    }
  }
  __syncthreads();

  const float* OfA = (const float*)pool;
#pragma unroll
  for (int k = 0; k < NQF * 2; k++) {
    int e = t + k * 256;
    int q = e >> 5, d = e & 31;
    float m0 = mlb[0][0][q], m1 = mlb[0][1][q], m2 = mlb[0][2][q], m3 = mlb[0][3][q];
    float M = fmaxf(fmaxf(m0, m1), fmaxf(m2, m3));
    float c0 = __expf(m0 - M), c1 = __expf(m1 - M), c2 = __expf(m2 - M), c3 = __expf(m3 - M);
    float lt = c0 * mlb[1][0][q] + c1 * mlb[1][1][q] + c2 * mlb[1][2][q] + c3 * mlb[1][3][q];
    int di = q * 32 + d;
    float v = c0 * OfA[di] + c1 * OfA[2048 + di] +
              c2 * OfA[4096 + di] + c3 * OfA[6144 + di];
    Ot[((size_t)b * Pq + q0 + q) * DIM + h * HD + d] = f2bf(v / lt);
  }
}

// ==== k_attn: fused x+y flash attention. grid (96, NH, B) ====
__global__ __launch_bounds__(256) void k_attn(u16* __restrict__ ws) {
  __shared__ __align__(16) u16 pool[16384];
  __shared__ float mlb[2][4][64];
  const int h = blockIdx.y, b = blockIdx.z;
  if (blockIdx.x < 64) {
    attn_core<4>(ws + OFF_QPX, ws + OFF_KPY, ws + OFF_VCY, ws + OFF_OTX,
                 PX, PY, blockIdx.x * 64, h, b, pool, mlb);
  } else {
    attn_core<2>(ws + OFF_QPY, ws + OFF_KPX, ws + OFF_VCX, ws + OFF_OTY,
                 PY, PX, (blockIdx.x - 64) * 32, h, b, pool, mlb);
  }
}

// ==== k_proj: fused x+y projection + bias + residual -> out ====
// grid (80, 8, B): bx<64 -> x (needs by<4), else y.
__global__ __launch_bounds__(256) void k_proj(
    u16* __restrict__ ws, void* __restrict__ outv,
    const void* __restrict__ resx, const void* __restrict__ resy) {
  const u16 *W, *A, *bias; const void* res; int OT, P, pxb; size_t out_off;
  if (blockIdx.x < 64) {
    if (blockIdx.y >= 4) return;
    W = ws + OFF_CWPX; A = ws + OFF_OTX; bias = ws + OFF_CBPX;
    res = resx; OT = CX; P = PX; pxb = blockIdx.x; out_off = 0;
  } else {
    W = ws + OFF_CWPY; A = ws + OFF_OTY; bias = ws + OFF_CBPY;
    res = resy; OT = CY; P = PY; pxb = blockIdx.x - 64;
    out_off = (size_t)B * CX * PX;
  }
  const bool f32io = is_f32(res);
  const int t = threadIdx.x;
  const int lane = t & 63, w = t >> 6;
  const int ql = lane & 15, quad = lane >> 4;
  const int p_w = pxb * 64 + (w & 1) * 32;
  const int o_w = blockIdx.y * 64 + (w >> 1) * 32;
  const int b = blockIdx.z;

  const u16* wr0 = W + (size_t)(o_w + ql) * DIM;
  const u16* wr1 = W + (size_t)(o_w + 16 + ql) * DIM;
  const u16* xr0 = A + ((size_t)b * P + p_w + ql) * DIM;
  const u16* xr1 = A + ((size_t)b * P + p_w + 16 + ql) * DIM;

  union U { uint4 u; short8 s; };
  f32x4 acc[2][2];
#pragma unroll
  for (int i = 0; i < 2; i++)
#pragma unroll
    for (int j = 0; j < 2; j++) acc[i][j] = (f32x4){0.f, 0.f, 0.f, 0.f};

#pragma unroll
  for (int c0 = 0; c0 < DIM; c0 += 32) {
    int off = c0 + quad * 8;
    U a0, a1, b0, b1;
    a0.u = *(const uint4*)&wr0[off];
    a1.u = *(const uint4*)&wr1[off];
    b0.u = *(const uint4*)&xr0[off];
    b1.u = *(const uint4*)&xr1[off];
    acc[0][0] = __builtin_amdgcn_mfma_f32_16x16x32_bf16(a0.s, b0.s, acc[0][0], 0, 0, 0);
    acc[0][1] = __builtin_amdgcn_mfma_f32_16x16x32_bf16(a0.s, b1.s, acc[0][1], 0, 0, 0);
    acc[1][0] = __builtin_amdgcn_mfma_f32_16x16x32_bf16(a1.s, b0.s, acc[1][0], 0, 0, 0);
    acc[1][1] = __builtin_amdgcn_mfma_f32_16x16x32_bf16(a1.s, b1.s, acc[1][1], 0, 0, 0);
  }

#pragma unroll
  for (int oi = 0; oi < 2; oi++)
#pragma unroll
    for (int pi = 0; pi < 2; pi++) {
      int p = p_w + pi * 16 + ql;
      f32x4 a = acc[oi][pi];
#pragma unroll
      for (int r = 0; r < 4; r++) {
        int o = o_w + oi * 16 + quad * 4 + r;
        float bv = bf2f(bias[o]);
        size_t idx = ((size_t)b * OT + o) * P + p;
        float rv = f32io ? ((const float*)res)[idx] : bf2f(((const u16*)res)[idx]);
        float v = a[r] + bv + rv;
        if (f32io) ((float*)outv)[out_off + idx] = v;
        else       ((u16*)outv)[out_off + idx] = f2bf(v);
      }
    }
}

extern "C" void kernel_launch(void* const* d_in, const int* in_sizes, int n_in,
                              void* d_out, int out_size, void* d_ws, size_t ws_size,
                              hipStream_t stream) {
  (void)in_sizes; (void)n_in; (void)out_size; (void)ws_size;
  u16* ws = (u16*)d_ws;

  k_prep<<<dim3(XPX_BLKS + XPY_BLKS + 196), 256, 0, stream>>>(
      d_in[0], d_in[1], d_in[2], d_in[3], d_in[4], d_in[5],
      d_in[6], d_in[7], d_in[8], d_in[9], ws);
  k_qkv<<<dim3(80, 6, B), 256, 0, stream>>>(ws);
  k_attn<<<dim3(96, NH, B), 256, 0, stream>>>(ws);
  k_proj<<<dim3(80, 8, B), 256, 0, stream>>>(ws, d_out, d_in[0], d_in[1]);
}

// Round 12
// 150.369 us; speedup vs baseline: 1.3888x; 1.0841x over previous
//
#include <hip/hip_runtime.h>
#include <hip/hip_bf16.h>
#include <cstdint>

#define B 2
#define NH 4
#define HD 32
#define DIM 128
#define CX 256
#define CY 512
#define PX 4096
#define PY 1024
#define QKV 384
#define GAMMA 0.17677669529663687f

typedef unsigned short u16;
typedef unsigned int u32;

using short8 = __attribute__((ext_vector_type(8))) short;
using f32x4  = __attribute__((ext_vector_type(4))) float;

__device__ __forceinline__ float bf2f(u32 h) {
  union { u32 u; float f; } v; v.u = (h & 0xffffu) << 16; return v.f;
}
__device__ __forceinline__ u16 f2bf(float f) {
  u32 u = __float_as_uint(f);
  u32 r = (u + 0x7fffu + ((u >> 16) & 1u)) >> 16;
  return (u16)r;
}
// per-wave dtype sample: f32 buffers have ~45% huge-exponent u16 patterns at
// even indices; bf16 data (|v|<=8) has none. 64 samples -> P[miss] ~ 3e-17.
__device__ __forceinline__ bool is_f32(const void* src) {
  u32 u = ((const u16*)src)[2 * (threadIdx.x & 63)];
  return __ballot((u & 0x7F80u) >= 0x4600u) != 0ull;
}

#define N_X   (B * CX * PX)
#define N_Y   (B * CY * PY)
#define N_WX  (QKV * CX)
#define N_BX  (QKV)
#define N_WY  (QKV * CY)
#define N_BY  (QKV)
#define N_WPX (CX * DIM)
#define N_BPX (CX)
#define N_WPY (CY * DIM)
#define N_BPY (CY)

// ---- workspace layout (u16 element offsets, all 16B-aligned) ----
enum : size_t {
  OFF_CWX   = 0,
  OFF_CBX   = OFF_CWX  + N_WX,
  OFF_CWY   = OFF_CBX  + N_BX,
  OFF_CBY   = OFF_CWY  + N_WY,
  OFF_CWPX  = OFF_CBY  + N_BY,
  OFF_CBPX  = OFF_CWPX + N_WPX,
  OFF_CWPY  = OFF_CBPX + N_BPX,
  OFF_CBPY  = OFF_CWPY + N_WPY,
  OFF_XT    = OFF_CBPY + N_BPY,                    // [B][PX][CX]
  OFF_YT    = OFF_XT   + (size_t)B * PX * CX,      // [B][PY][CY]
  OFF_QPX   = OFF_YT   + (size_t)B * PY * CY,      // [B][NH][PX][32] q packed (scaled)
  OFF_KPX   = OFF_QPX  + (size_t)B * NH * PX * HD, // [B][NH][PX][32]
  OFF_QPY   = OFF_KPX  + (size_t)B * NH * PX * HD, // [B][NH][PY][32]
  OFF_KPY   = OFF_QPY  + (size_t)B * NH * PY * HD, // [B][NH][PY][32]
  OFF_VCX   = OFF_KPY  + (size_t)B * NH * PY * HD, // [B][128][PX]
  OFF_VCY   = OFF_VCX  + (size_t)B * DIM * PX,     // [B][128][PY]
  OFF_OTX   = OFF_VCY  + (size_t)B * DIM * PY,     // [B][PX][128]
  OFF_OTY   = OFF_OTX  + (size_t)B * PX * DIM,     // [B][PY][128]
  WS_END    = OFF_OTY  + (size_t)B * PY * DIM,
};

// ==== k_prep: fused dtype-detect + weight/bias convert + input transposes ====
#define XPX_BLKS 2048
#define XPY_BLKS 1024
__global__ __launch_bounds__(256) void k_prep(
    const void* x, const void* y, const void* wx, const void* bx,
    const void* wy, const void* by, const void* wpx, const void* bpx,
    const void* wpy, const void* bpy, u16* __restrict__ ws) {
  const int id = blockIdx.x;
  if (id < XPX_BLKS + XPY_BLKS) {
    __shared__ u16 tile[32][33];
    const void* src; u16* dst; int C, P, p_t, c_t, b;
    if (id < XPX_BLKS) {
      src = x; dst = ws + OFF_XT; C = CX; P = PX;
      p_t = id & 127; c_t = (id >> 7) & 7; b = id >> 10;
    } else {
      int id2 = id - XPX_BLKS;
      src = y; dst = ws + OFF_YT; C = CY; P = PY;
      p_t = id2 & 31; c_t = (id2 >> 5) & 15; b = id2 >> 9;
    }
    const bool f32in = is_f32(src);
    const int tx = threadIdx.x & 31, ty = threadIdx.x >> 5;
    const int p0 = p_t * 32, c0 = c_t * 32;
#pragma unroll
    for (int i = 0; i < 4; i++) {
      int cl = ty * 4 + i;
      size_t sidx = ((size_t)b * C + c0 + cl) * P + p0 + tx;
      u16 v = f32in ? f2bf(((const float*)src)[sidx]) : ((const u16*)src)[sidx];
      tile[cl][tx] = v;
    }
    __syncthreads();
#pragma unroll
    for (int i = 0; i < 4; i++) {
      int pl = ty * 4 + i;
      dst[((size_t)b * P + p0 + pl) * C + c0 + tx] = tile[tx][pl];
    }
  } else {
    int wid = id - (XPX_BLKS + XPY_BLKS);
    const void* src; size_t dstoff; int n, base;
    if      (wid < 48)  { src = wx;  dstoff = OFF_CWX;  n = N_WX;  base = 0; }
    else if (wid < 49)  { src = bx;  dstoff = OFF_CBX;  n = N_BX;  base = 48; }
    else if (wid < 145) { src = wy;  dstoff = OFF_CWY;  n = N_WY;  base = 49; }
    else if (wid < 146) { src = by;  dstoff = OFF_CBY;  n = N_BY;  base = 145; }
    else if (wid < 162) { src = wpx; dstoff = OFF_CWPX; n = N_WPX; base = 146; }
    else if (wid < 163) { src = bpx; dstoff = OFF_CBPX; n = N_BPX; base = 162; }
    else if (wid < 195) { src = wpy; dstoff = OFF_CWPY; n = N_WPY; base = 163; }
    else                { src = bpy; dstoff = OFF_CBPY; n = N_BPY; base = 195; }
    const bool f32in = is_f32(src);
    int e0 = (wid - base) * 2048 + threadIdx.x * 8;
    if (e0 >= n) return;
    u16* dst = ws + dstoff + e0;
    if (f32in) {
      const float* s = (const float*)src + e0;
      float4 a = *(const float4*)s;
      float4 bq = *(const float4*)(s + 4);
      ushort4 o0, o1;
      o0.x = f2bf(a.x);  o0.y = f2bf(a.y);  o0.z = f2bf(a.z);  o0.w = f2bf(a.w);
      o1.x = f2bf(bq.x); o1.y = f2bf(bq.y); o1.z = f2bf(bq.z); o1.w = f2bf(bq.w);
      *(ushort4*)dst = o0;
      *(ushort4*)(dst + 4) = o1;
    } else {
      uint4 v = *(const uint4*)((const u16*)src + e0);
      *(uint4*)dst = v;
    }
  }
}

// ==== k_qkv: fused x+y qkv GEMMs (MFMA, no LDS) — unchanged from R11 ====
__global__ __launch_bounds__(256) void k_qkv(u16* __restrict__ ws) {
  const int t = threadIdx.x;
  const int lane = t & 63, w = t >> 6;
  const int ql = lane & 15, quad = lane >> 4;
  const int b = blockIdx.z;

  const u16 *W, *Xt, *bias; u16 *qp, *kp, *vc; int C, P, pxb;
  if (blockIdx.x < 64) {
    W = ws + OFF_CWX; Xt = ws + OFF_XT; bias = ws + OFF_CBX;
    qp = ws + OFF_QPX; kp = ws + OFF_KPX; vc = ws + OFF_VCX;
    C = CX; P = PX; pxb = blockIdx.x;
  } else {
    W = ws + OFF_CWY; Xt = ws + OFF_YT; bias = ws + OFF_CBY;
    qp = ws + OFF_QPY; kp = ws + OFF_KPY; vc = ws + OFF_VCY;
    C = CY; P = PY; pxb = blockIdx.x - 64;
  }
  const int p_w = pxb * 64 + (w & 1) * 32;
  const int o_w = blockIdx.y * 64 + (w >> 1) * 32;

  const u16* wr0 = W + (size_t)(o_w + ql) * C;
  const u16* wr1 = W + (size_t)(o_w + 16 + ql) * C;
  const u16* xr0 = Xt + ((size_t)b * P + p_w + ql) * C;
  const u16* xr1 = Xt + ((size_t)b * P + p_w + 16 + ql) * C;

  union U { uint4 u; short8 s; };
  f32x4 acc[2][2];
#pragma unroll
  for (int i = 0; i < 2; i++)
#pragma unroll
    for (int j = 0; j < 2; j++) acc[i][j] = (f32x4){0.f, 0.f, 0.f, 0.f};

#pragma unroll 4
  for (int c0 = 0; c0 < C; c0 += 32) {
    int off = c0 + quad * 8;
    U a0, a1, b0, b1;
    a0.u = *(const uint4*)&wr0[off];
    a1.u = *(const uint4*)&wr1[off];
    b0.u = *(const uint4*)&xr0[off];
    b1.u = *(const uint4*)&xr1[off];
    acc[0][0] = __builtin_amdgcn_mfma_f32_16x16x32_bf16(a0.s, b0.s, acc[0][0], 0, 0, 0);
    acc[0][1] = __builtin_amdgcn_mfma_f32_16x16x32_bf16(a0.s, b1.s, acc[0][1], 0, 0, 0);
    acc[1][0] = __builtin_amdgcn_mfma_f32_16x16x32_bf16(a1.s, b0.s, acc[1][0], 0, 0, 0);
    acc[1][1] = __builtin_amdgcn_mfma_f32_16x16x32_bf16(a1.s, b1.s, acc[1][1], 0, 0, 0);
  }

  float bs[2][4];
#pragma unroll
  for (int oi = 0; oi < 2; oi++)
#pragma unroll
    for (int r = 0; r < 4; r++)
      bs[oi][r] = bf2f(bias[o_w + oi * 16 + quad * 4 + r]);

  if (blockIdx.y < 4) {
    bool isq = blockIdx.y < 2;
    float scale = isq ? GAMMA : 1.0f;
    u16* dstT = isq ? qp : kp;
#pragma unroll
    for (int oi = 0; oi < 2; oi++)
#pragma unroll
      for (int pi = 0; pi < 2; pi++) {
        int p = p_w + pi * 16 + ql;
        int o = o_w + oi * 16 + quad * 4 - (isq ? 0 : 128);
        int hh = o >> 5, d = o & 31;
        f32x4 a = acc[oi][pi];
        uint2 pk;
        pk.x = (u32)f2bf((a[0] + bs[oi][0]) * scale) |
               ((u32)f2bf((a[1] + bs[oi][1]) * scale) << 16);
        pk.y = (u32)f2bf((a[2] + bs[oi][2]) * scale) |
               ((u32)f2bf((a[3] + bs[oi][3]) * scale) << 16);
        *(uint2*)&dstT[((size_t)(b * NH + hh) * P + p) * HD + d] = pk;
      }
  } else {
#pragma unroll
    for (int oi = 0; oi < 2; oi++)
#pragma unroll
      for (int pi = 0; pi < 2; pi++) {
        int p = p_w + pi * 16 + ql;
        f32x4 a = acc[oi][pi];
#pragma unroll
        for (int r = 0; r < 4; r++) {
          int o = o_w + oi * 16 + quad * 4 + r - 256;
          vc[((size_t)b * DIM + o) * P + p] = f2bf(a[r] + bs[oi][r]);
        }
      }
  }
}

// ==== attention core v8: DIRECT global register loads (no LDS staging, no
// sched_barrier, no manual waitcnt — compiler schedules). Permuted-K applied
// in the GLOBAL address (token-major Kp makes it one dwordx4 per fragment).
// P stays in-lane (QK^T C-layout == PV B-layout); packed via v_perm (trunc).
// LDS used only for the final 4-wave merge. ====
template <int NQF>
__device__ __forceinline__ void attn_core(
    const u16* __restrict__ Qp, const u16* __restrict__ Kp,
    const u16* __restrict__ Vc, u16* __restrict__ Ot, int Pq, int Pk,
    int q0, int h, int b, u16* pool, float (*mlb)[4][64]) {
  const int t = threadIdx.x;
  const int lane = t & 63, w = t >> 6;
  const int ql = lane & 15, quad = lane >> 4;

  union U { uint4 u; short8 s; };
  U qf[NQF];
#pragma unroll
  for (int qi = 0; qi < NQF; qi++)
    qf[qi].u = *(const uint4*)&Qp[((size_t)(b * NH + h) * Pq + q0 + qi * 16 + ql) * HD + quad * 8];

  const int kspan = Pk >> 2;
  const int kk0 = w * kspan;
  const int niter = kspan >> 5;
  const int f0 = ((ql >> 2) << 3) | (ql & 3);   // key permutation

  // ka: A[key=k0+f0(ql)][d=quad*8..]; kb: key+4. One dwordx4 each.
  const u16* kbase = Kp + ((size_t)(b * NH + h) * Pk + kk0 + f0) * HD + quad * 8;
  // va/vb: A[d=ql(/16+ql)][key=k0+quad*8..] from channel-major Vc.
  const u16* v0base = Vc + ((size_t)(b * DIM + h * HD + ql)) * Pk + kk0 + quad * 8;
  const u16* v1base = v0base + (size_t)16 * Pk;

  U ka, kb, va, vb, kan, kbn, van, vbn;
  ka.u = *(const uint4*)&kbase[0];
  kb.u = *(const uint4*)&kbase[4 * HD];
  va.u = *(const uint4*)&v0base[0];
  vb.u = *(const uint4*)&v1base[0];

  f32x4 o0[NQF], o1[NQF];
  float m_run[NQF], l_run[NQF];
#pragma unroll
  for (int qi = 0; qi < NQF; qi++) {
    o0[qi] = (f32x4){0.f, 0.f, 0.f, 0.f};
    o1[qi] = (f32x4){0.f, 0.f, 0.f, 0.f};
    m_run[qi] = -1e30f; l_run[qi] = 0.f;
  }

  for (int it = 0; it < niter; it++) {
    if (it + 1 < niter) {
      size_t go = (size_t)(it + 1) * 32;
      kan.u = *(const uint4*)&kbase[go * HD];
      kbn.u = *(const uint4*)&kbase[(go + 4) * HD];
      van.u = *(const uint4*)&v0base[go];
      vbn.u = *(const uint4*)&v1base[go];
    }

#pragma unroll
    for (int qi = 0; qi < NQF; qi++) {
      f32x4 z = {0.f, 0.f, 0.f, 0.f};
      f32x4 st0 = __builtin_amdgcn_mfma_f32_16x16x32_bf16(ka.s, qf[qi].s, z, 0, 0, 0);
      f32x4 st1 = __builtin_amdgcn_mfma_f32_16x16x32_bf16(kb.s, qf[qi].s, z, 0, 0, 0);

      // lane owns q=ql, keys kk0 + it*32 + quad*8 + {0..7}
      float s[8] = {st0[0], st0[1], st0[2], st0[3], st1[0], st1[1], st1[2], st1[3]};
      float cm = fmaxf(fmaxf(fmaxf(s[0], s[1]), fmaxf(s[2], s[3])),
                       fmaxf(fmaxf(s[4], s[5]), fmaxf(s[6], s[7])));
      cm = fmaxf(cm, __shfl_xor(cm, 16));
      cm = fmaxf(cm, __shfl_xor(cm, 32));
      float m_new = fmaxf(m_run[qi], cm);
      float alpha = __expf(m_run[qi] - m_new);
      float p[8], ls = 0.f;
#pragma unroll
      for (int i = 0; i < 8; i++) { p[i] = __expf(s[i] - m_new); ls += p[i]; }
      ls += __shfl_xor(ls, 16);
      ls += __shfl_xor(ls, 32);
      l_run[qi] = l_run[qi] * alpha + ls;
      m_run[qi] = m_new;
#pragma unroll
      for (int r = 0; r < 4; r++) { o0[qi][r] *= alpha; o1[qi][r] *= alpha; }

      // pack P (bf16 truncation) via v_perm: 1 op per pair
      U pf;
      pf.u.x = __builtin_amdgcn_perm(__float_as_uint(p[1]), __float_as_uint(p[0]), 0x07060302u);
      pf.u.y = __builtin_amdgcn_perm(__float_as_uint(p[3]), __float_as_uint(p[2]), 0x07060302u);
      pf.u.z = __builtin_amdgcn_perm(__float_as_uint(p[5]), __float_as_uint(p[4]), 0x07060302u);
      pf.u.w = __builtin_amdgcn_perm(__float_as_uint(p[7]), __float_as_uint(p[6]), 0x07060302u);

      o0[qi] = __builtin_amdgcn_mfma_f32_16x16x32_bf16(va.s, pf.s, o0[qi], 0, 0, 0);
      o1[qi] = __builtin_amdgcn_mfma_f32_16x16x32_bf16(vb.s, pf.s, o1[qi], 0, 0, 0);
    }
    ka = kan; kb = kbn; va = van; vb = vbn;
  }

  // merge 4 wave-partials: each wave's overlay in its OWN 8KB pool region
  float* Of = (float*)(pool + (size_t)w * 4096);
#pragma unroll
  for (int qi = 0; qi < NQF; qi++) {
#pragma unroll
    for (int r = 0; r < 4; r++) {
      Of[(qi * 16 + ql) * 32 + quad * 4 + r] = o0[qi][r];
      Of[(qi * 16 + ql) * 32 + 16 + quad * 4 + r] = o1[qi][r];
    }
    if (quad == 0) {
      mlb[0][w][qi * 16 + ql] = m_run[qi];
      mlb[1][w][qi * 16 + ql] = l_run[qi];
    }
  }
  __syncthreads();

  const float* OfA = (const float*)pool;
#pragma unroll
  for (int k = 0; k < NQF * 2; k++) {
    int e = t + k * 256;
    int q = e >> 5, d = e & 31;
    float m0 = mlb[0][0][q], m1 = mlb[0][1][q], m2 = mlb[0][2][q], m3 = mlb[0][3][q];
    float M = fmaxf(fmaxf(m0, m1), fmaxf(m2, m3));
    float c0 = __expf(m0 - M), c1 = __expf(m1 - M), c2 = __expf(m2 - M), c3 = __expf(m3 - M);
    float lt = c0 * mlb[1][0][q] + c1 * mlb[1][1][q] + c2 * mlb[1][2][q] + c3 * mlb[1][3][q];
    int di = q * 32 + d;
    float v = c0 * OfA[di] + c1 * OfA[2048 + di] +
              c2 * OfA[4096 + di] + c3 * OfA[6144 + di];
    Ot[((size_t)b * Pq + q0 + q) * DIM + h * HD + d] = f2bf(v / lt);
  }
}

// ==== k_attn: fused x+y flash attention. grid (96, NH, B) ====
__global__ __launch_bounds__(256) void k_attn(u16* __restrict__ ws) {
  __shared__ __align__(16) u16 pool[16384];
  __shared__ float mlb[2][4][64];
  const int h = blockIdx.y, b = blockIdx.z;
  if (blockIdx.x < 64) {
    attn_core<4>(ws + OFF_QPX, ws + OFF_KPY, ws + OFF_VCY, ws + OFF_OTX,
                 PX, PY, blockIdx.x * 64, h, b, pool, mlb);
  } else {
    attn_core<2>(ws + OFF_QPY, ws + OFF_KPX, ws + OFF_VCX, ws + OFF_OTY,
                 PY, PX, (blockIdx.x - 64) * 32, h, b, pool, mlb);
  }
}

// ==== k_proj: fused x+y projection + bias + residual -> out (R11) ====
__global__ __launch_bounds__(256) void k_proj(
    u16* __restrict__ ws, void* __restrict__ outv,
    const void* __restrict__ resx, const void* __restrict__ resy) {
  const u16 *W, *A, *bias; const void* res; int OT, P, pxb; size_t out_off;
  if (blockIdx.x < 64) {
    if (blockIdx.y >= 4) return;
    W = ws + OFF_CWPX; A = ws + OFF_OTX; bias = ws + OFF_CBPX;
    res = resx; OT = CX; P = PX; pxb = blockIdx.x; out_off = 0;
  } else {
    W = ws + OFF_CWPY; A = ws + OFF_OTY; bias = ws + OFF_CBPY;
    res = resy; OT = CY; P = PY; pxb = blockIdx.x - 64;
    out_off = (size_t)B * CX * PX;
  }
  const bool f32io = is_f32(res);
  const int t = threadIdx.x;
  const int lane = t & 63, w = t >> 6;
  const int ql = lane & 15, quad = lane >> 4;
  const int p_w = pxb * 64 + (w & 1) * 32;
  const int o_w = blockIdx.y * 64 + (w >> 1) * 32;
  const int b = blockIdx.z;

  const u16* wr0 = W + (size_t)(o_w + ql) * DIM;
  const u16* wr1 = W + (size_t)(o_w + 16 + ql) * DIM;
  const u16* xr0 = A + ((size_t)b * P + p_w + ql) * DIM;
  const u16* xr1 = A + ((size_t)b * P + p_w + 16 + ql) * DIM;

  union U { uint4 u; short8 s; };
  f32x4 acc[2][2];
#pragma unroll
  for (int i = 0; i < 2; i++)
#pragma unroll
    for (int j = 0; j < 2; j++) acc[i][j] = (f32x4){0.f, 0.f, 0.f, 0.f};

#pragma unroll
  for (int c0 = 0; c0 < DIM; c0 += 32) {
    int off = c0 + quad * 8;
    U a0, a1, b0, b1;
    a0.u = *(const uint4*)&wr0[off];
    a1.u = *(const uint4*)&wr1[off];
    b0.u = *(const uint4*)&xr0[off];
    b1.u = *(const uint4*)&xr1[off];
    acc[0][0] = __builtin_amdgcn_mfma_f32_16x16x32_bf16(a0.s, b0.s, acc[0][0], 0, 0, 0);
    acc[0][1] = __builtin_amdgcn_mfma_f32_16x16x32_bf16(a0.s, b1.s, acc[0][1], 0, 0, 0);
    acc[1][0] = __builtin_amdgcn_mfma_f32_16x16x32_bf16(a1.s, b0.s, acc[1][0], 0, 0, 0);
    acc[1][1] = __builtin_amdgcn_mfma_f32_16x16x32_bf16(a1.s, b1.s, acc[1][1], 0, 0, 0);
  }

#pragma unroll
  for (int oi = 0; oi < 2; oi++)
#pragma unroll
    for (int pi = 0; pi < 2; pi++) {
      int p = p_w + pi * 16 + ql;
      f32x4 a = acc[oi][pi];
#pragma unroll
      for (int r = 0; r < 4; r++) {
        int o = o_w + oi * 16 + quad * 4 + r;
        float bv = bf2f(bias[o]);
        size_t idx = ((size_t)b * OT + o) * P + p;
        float rv = f32io ? ((const float*)res)[idx] : bf2f(((const u16*)res)[idx]);
        float v = a[r] + bv + rv;
        if (f32io) ((float*)outv)[out_off + idx] = v;
        else       ((u16*)outv)[out_off + idx] = f2bf(v);
      }
    }
}

extern "C" void kernel_launch(void* const* d_in, const int* in_sizes, int n_in,
                              void* d_out, int out_size, void* d_ws, size_t ws_size,
                              hipStream_t stream) {
  (void)in_sizes; (void)n_in; (void)out_size; (void)ws_size;
  u16* ws = (u16*)d_ws;

  k_prep<<<dim3(XPX_BLKS + XPY_BLKS + 196), 256, 0, stream>>>(
      d_in[0], d_in[1], d_in[2], d_in[3], d_in[4], d_in[5],
      d_in[6], d_in[7], d_in[8], d_in[9], ws);
  k_qkv<<<dim3(80, 6, B), 256, 0, stream>>>(ws);
  k_attn<<<dim3(96, NH, B), 256, 0, stream>>>(ws);
  k_proj<<<dim3(80, 8, B), 256, 0, stream>>>(ws, d_out, d_in[0], d_in[1]);
}